// Round 6
// baseline (284.532 us; speedup 1.0000x reference)
//
#include <hip/hip_runtime.h>
#include <stdint.h>

#define NV 50000
#define NE 10000
#define HD 256
#define NP 400000

#define SE 88     // bkt_e row stride (avg deg 40; P[any row >88] ~ 1e-7)
#define SV 36     // bkt_v row stride (avg deg 8;  P[any row >36] ~ 3e-9)

#define NCH 128           // chunks for the no-atomic counting sort
#define CHP (NP / NCH)    // 3125 pairs per chunk
#define NW  15000         // packed words (4 rows/word, 8-bit ctrs); e:[0,2500) v:[2500,15000)
#define NWE 2500
#define NWV 12500

#define PREP_HBLK NCH     // hist blocks (LDS-only, no device atomics)
#define PREP_WBLK 16      // W1+W2 convert: 131072 elems / 8192
#define PREP_VBLK 1563    // v convert: 12.8M elems / 8192 (last block partial)

typedef short short8 __attribute__((ext_vector_type(8)));
typedef short short4v __attribute__((ext_vector_type(4)));
typedef float f32x4 __attribute__((ext_vector_type(4)));

__device__ __forceinline__ short f2bf(float f) {
    unsigned int u = __builtin_bit_cast(unsigned int, f);
    u += 0x7FFFu + ((u >> 16) & 1u);   // round-to-nearest-even
    return (short)(u >> 16);
}
__device__ __forceinline__ float bf2f(short s) {
    unsigned int u = ((unsigned int)(unsigned short)s) << 16;
    return __builtin_bit_cast(float, u);
}
__device__ __forceinline__ float rfl_f(int x) {
    return __builtin_bit_cast(float, __builtin_amdgcn_readfirstlane(x));
}

// ---------------------------------------------------------------------------
// prep: fused per-chunk histogram (LDS, packed 8-bit) + (W1,W2 -> bf16) +
// (v -> bf16). Zero device-scope atomics. Hist blocks dispatched first.
// ---------------------------------------------------------------------------
__global__ __launch_bounds__(1024) void prep_kernel(
    const float* __restrict__ v, const float* __restrict__ W1, const float* __restrict__ W2,
    const int* __restrict__ eidx, const int* __restrict__ vidx,
    short* __restrict__ v_bf, short* __restrict__ W_bf,    // W_bf: [2*256*256]
    int* __restrict__ cnt8,                                // [NCH][NW] packed counts
    int conv_v)
{
    __shared__ int h[NW];   // 60 KB
    int b = blockIdx.x;
    int tid = threadIdx.x;
    if (b < PREP_HBLK) {
        // ---- per-chunk histogram over unified row space ----
        for (int w = tid; w < NW; w += 1024) h[w] = 0;
        __syncthreads();
        int base = b * CHP;
        for (int k = tid; k < CHP; k += 1024) {
            int p = base + k;
            int er = eidx[p];
            atomicAdd((unsigned*)&h[er >> 2], 1u << ((er & 3) * 8));
            int rv = 10000 + vidx[p];
            atomicAdd((unsigned*)&h[rv >> 2], 1u << ((rv & 3) * 8));
        }
        __syncthreads();
        for (int w = tid; w < NW; w += 1024) cnt8[b * NW + w] = h[w];
    } else if (b < PREP_HBLK + PREP_WBLK) {
        size_t i = (size_t)(b - PREP_HBLK) * 8192 + (size_t)tid * 8;
        const float* src = (i < 65536) ? (W1 + i) : (W2 + (i - 65536));
        float4 a0 = *(const float4*)src;
        float4 a1 = *(const float4*)(src + 4);
        short8 s;
        s[0] = f2bf(a0.x); s[1] = f2bf(a0.y); s[2] = f2bf(a0.z); s[3] = f2bf(a0.w);
        s[4] = f2bf(a1.x); s[5] = f2bf(a1.y); s[6] = f2bf(a1.z); s[7] = f2bf(a1.w);
        *(short8*)(W_bf + i) = s;
    } else {
        if (!conv_v) return;
        size_t i = (size_t)(b - PREP_HBLK - PREP_WBLK) * 8192 + (size_t)tid * 8;
        if (i >= (size_t)NV * HD) return;
        float4 a0 = *(const float4*)(v + i);
        float4 a1 = *(const float4*)(v + i + 4);
        short8 s;
        s[0] = f2bf(a0.x); s[1] = f2bf(a0.y); s[2] = f2bf(a0.z); s[3] = f2bf(a0.w);
        s[4] = f2bf(a1.x); s[5] = f2bf(a1.y); s[6] = f2bf(a1.z); s[7] = f2bf(a1.w);
        *(short8*)(v_bf + i) = s;
    }
}

// ---------------------------------------------------------------------------
// scan: per-word SWAR exclusive prefix over chunks (byte lanes never carry:
// row totals <= 255). Overwrites cnt8 with per-chunk starts; emits totals.
// ---------------------------------------------------------------------------
__global__ __launch_bounds__(256) void scan_kernel(
    int* __restrict__ cnt8, int* __restrict__ cnt_e, int* __restrict__ cnt_v)
{
    int w = blockIdx.x * 256 + threadIdx.x;
    if (w >= NW) return;
    unsigned acc = 0;
#pragma unroll 8
    for (int c = 0; c < NCH; ++c) {
        unsigned x = (unsigned)cnt8[c * NW + w];
        cnt8[c * NW + w] = (int)acc;
        acc += x;
    }
    int r0 = w * 4;
    int4 t;
    t.x = acc & 0xFF; t.y = (acc >> 8) & 0xFF; t.z = (acc >> 16) & 0xFF; t.w = acc >> 24;
    if (r0 < 10000) *(int4*)&cnt_e[r0] = t;
    else            *(int4*)&cnt_v[r0 - 10000] = t;
}

// ---------------------------------------------------------------------------
// place: 256 blocks, e-side (b<NCH) and v-side (b>=NCH) split so each block
// does half the per-pair work. Exact slot via packed LDS fetch-add, then
// stores the gather metadata INLINE: {src_row, weight_bits}. Zero dev atomics.
// ---------------------------------------------------------------------------
__global__ __launch_bounds__(1024) void place_kernel(
    const int* __restrict__ eidx, const int* __restrict__ vidx,
    const int* __restrict__ pairs_v, const int* __restrict__ n_reg_w_bits,
    const int* __restrict__ pairs_e, const int* __restrict__ e_reg_w_bits,
    const int* __restrict__ cnt8,
    int2* __restrict__ bkt_e, int2* __restrict__ bkt_v)
{
    __shared__ int h[NWV];   // 50 KB (v-side); e-side uses first 2500 words
    int b = blockIdx.x;
    int tid = threadIdx.x;
    if (b < NCH) {
        // ---- edge side: chunk b ----
        int c = b;
        for (int w = tid; w < NWE; w += 1024) h[w] = cnt8[c * NW + w];
        __syncthreads();
        int base = c * CHP;
        for (int k = tid; k < CHP; k += 1024) {
            int p = base + k;
            int er = eidx[p];
            unsigned old = atomicAdd((unsigned*)&h[er >> 2], 1u << ((er & 3) * 8));
            int s = (old >> ((er & 3) * 8)) & 0xFF;
            if (s < SE) bkt_e[er * SE + s] = make_int2(pairs_v[p], n_reg_w_bits[p]);
        }
    } else {
        // ---- vertex side: chunk b-NCH ----
        int c = b - NCH;
        for (int w = tid; w < NWV; w += 1024) h[w] = cnt8[c * NW + NWE + w];
        __syncthreads();
        int base = c * CHP;
        for (int k = tid; k < CHP; k += 1024) {
            int p = base + k;
            int vr = vidx[p];
            unsigned old = atomicAdd((unsigned*)&h[vr >> 2], 1u << ((vr & 3) * 8));
            int s = (old >> ((vr & 3) * 8)) & 0xFF;
            if (s < SV) bkt_v[vr * SV + s] = make_int2(pairs_e[p], e_reg_w_bits[p]);
        }
    }
}

// ---------------------------------------------------------------------------
// GEMM: out_bf16[i][j] = relu(sum_k A[i][k]*W[j][k] + bias[j]) * rowscale[i]
// A: [M][256] f32 or bf16 (a_bf flag); W: [256][256] bf16 row-major.
// Grid over 64-row tiles; block loops 4 column tiles. bf16 MFMA 16x16x32,
// XOR-swizzled LDS; staging is pure b128 copy when a_bf=1 (no VALU repack).
// ---------------------------------------------------------------------------
__global__ __launch_bounds__(256) void gemm_rs(
    const void* __restrict__ Av, int a_bf,
    const short* __restrict__ Wb,
    const float* __restrict__ bias,
    const float* __restrict__ rowscale,
    short* __restrict__ out,          // bf16
    int M)
{
    __shared__ short As[64 * 256];
    __shared__ short Ws[64 * 256];
    const int tid  = threadIdx.x;
    const int row0 = blockIdx.x * 64;

    // stage A tile once
#pragma unroll
    for (int it = 0; it < 8; ++it) {
        int cl = it * 256 + tid;
        int r  = cl >> 5;
        int c  = cl & 31;
        int gr = row0 + r; gr = gr < M ? gr : M - 1;
        short8 ap;
        if (a_bf) {
            ap = *(const short8*)((const short*)Av + (size_t)gr * HD + (c << 3));
        } else {
            const float* asrc = (const float*)Av + (size_t)gr * HD + (c << 3);
            float4 a0 = *(const float4*)asrc;
            float4 a1 = *(const float4*)(asrc + 4);
            ap[0] = f2bf(a0.x); ap[1] = f2bf(a0.y); ap[2] = f2bf(a0.z); ap[3] = f2bf(a0.w);
            ap[4] = f2bf(a1.x); ap[5] = f2bf(a1.y); ap[6] = f2bf(a1.z); ap[7] = f2bf(a1.w);
        }
        *(short8*)&As[(r << 8) + ((c ^ (r & 7)) << 3)] = ap;
    }

    const int lane = tid & 63;
    const int wv   = tid >> 6;
    const int m16  = lane & 15;
    const int quad = lane >> 4;
    const int arow = (wv << 4) + m16;

    for (int ct = 0; ct < 4; ++ct) {
        __syncthreads();   // As staged (ct=0) / prior Ws fragment reads done (ct>0)
        // stage W column tile ct (bf16 -> straight swizzled copy)
#pragma unroll
        for (int it = 0; it < 8; ++it) {
            int cl = it * 256 + tid;
            int r  = cl >> 5;
            int c  = cl & 31;
            short8 wp = *(const short8*)(Wb + (size_t)((ct << 6) + r) * HD + (c << 3));
            *(short8*)&Ws[(r << 8) + ((c ^ (r & 7)) << 3)] = wp;
        }
        __syncthreads();

        f32x4 acc[4];
#pragma unroll
        for (int nt = 0; nt < 4; ++nt) acc[nt] = (f32x4){0.f, 0.f, 0.f, 0.f};

#pragma unroll
        for (int ks = 0; ks < 8; ++ks) {
            int c = (ks << 2) + quad;
            short8 afr = *(const short8*)&As[(arow << 8) + ((c ^ (arow & 7)) << 3)];
#pragma unroll
            for (int nt = 0; nt < 4; ++nt) {
                int brow = (nt << 4) + m16;
                short8 bfr = *(const short8*)&Ws[(brow << 8) + ((c ^ (m16 & 7)) << 3)];
                acc[nt] = __builtin_amdgcn_mfma_f32_16x16x32_bf16(afr, bfr, acc[nt], 0, 0, 0);
            }
        }

#pragma unroll
        for (int r = 0; r < 4; ++r) {
            int row = row0 + (wv << 4) + (quad << 2) + r;
            if (row < M) {
                float rs = rowscale[row];
#pragma unroll
                for (int nt = 0; nt < 4; ++nt) {
                    int col = (ct << 6) + (nt << 4) + m16;
                    float val = acc[nt][r] + bias[col];
                    val = fmaxf(val, 0.0f) * rs;
                    out[(size_t)row * HD + col] = f2bf(val);
                }
            }
        }
    }
}

// ---------------------------------------------------------------------------
// gather core: bucket metadata {src,w} is read with WAVE-UNIFORM int4 loads
// (2 entries / 16 B; 8 entries share one 64B line -> L1 hits) and moved to
// SGPRs via readfirstlane. No ds_bpermute broadcasts, and the msg-row load
// becomes SGPR-base + lane offset (minimal VALU address math).
// ---------------------------------------------------------------------------
__device__ __forceinline__ void gather_core(
    const short* __restrict__ msg, const int2* __restrict__ bkt,
    int i, int end, int lane, float4& acc)
{
    int j = i;
    for (; j + 4 <= end; j += 4) {
        int4 q0 = *(const int4*)(bkt + j);       // entries j, j+1   (uniform addr)
        int4 q1 = *(const int4*)(bkt + j + 2);   // entries j+2, j+3 (uniform addr)
        int   s0 = __builtin_amdgcn_readfirstlane(q0.x);
        float w0 = rfl_f(q0.y);
        int   s1 = __builtin_amdgcn_readfirstlane(q0.z);
        float w1 = rfl_f(q0.w);
        int   s2 = __builtin_amdgcn_readfirstlane(q1.x);
        float w2 = rfl_f(q1.y);
        int   s3 = __builtin_amdgcn_readfirstlane(q1.z);
        float w3 = rfl_f(q1.w);
        short4v m0 = *(const short4v*)(msg + ((size_t)s0 << 8) + (lane << 2));
        short4v m1 = *(const short4v*)(msg + ((size_t)s1 << 8) + (lane << 2));
        short4v m2 = *(const short4v*)(msg + ((size_t)s2 << 8) + (lane << 2));
        short4v m3 = *(const short4v*)(msg + ((size_t)s3 << 8) + (lane << 2));
        acc.x += bf2f(m0[0]) * w0; acc.y += bf2f(m0[1]) * w0;
        acc.z += bf2f(m0[2]) * w0; acc.w += bf2f(m0[3]) * w0;
        acc.x += bf2f(m1[0]) * w1; acc.y += bf2f(m1[1]) * w1;
        acc.z += bf2f(m1[2]) * w1; acc.w += bf2f(m1[3]) * w1;
        acc.x += bf2f(m2[0]) * w2; acc.y += bf2f(m2[1]) * w2;
        acc.z += bf2f(m2[2]) * w2; acc.w += bf2f(m2[3]) * w2;
        acc.x += bf2f(m3[0]) * w3; acc.y += bf2f(m3[1]) * w3;
        acc.z += bf2f(m3[2]) * w3; acc.w += bf2f(m3[3]) * w3;
    }
    for (; j < end; ++j) {
        int2 q = bkt[j];                          // uniform addr
        int   s0 = __builtin_amdgcn_readfirstlane(q.x);
        float w0 = rfl_f(q.y);
        short4v m0 = *(const short4v*)(msg + ((size_t)s0 << 8) + (lane << 2));
        acc.x += bf2f(m0[0]) * w0; acc.y += bf2f(m0[1]) * w0;
        acc.z += bf2f(m0[2]) * w0; acc.w += bf2f(m0[3]) * w0;
    }
}

__global__ __launch_bounds__(256) void gather_e(
    const short* __restrict__ msg,       // [NV][256] bf16
    const int2* __restrict__ bkt,        // [NE][SE] {src,w}
    const int* __restrict__ cnt,
    const float* __restrict__ e_in, const float* __restrict__ reg_sum,
    float* __restrict__ out, short* __restrict__ out_bf)   // out_bf may be null
{
    int r    = (blockIdx.x << 2) + (threadIdx.x >> 6);
    int lane = threadIdx.x & 63;
    float4 acc = ((const float4*)(e_in + (size_t)r * HD))[lane];
    int n = cnt[r]; n = n < SE ? n : SE;
    int i0 = r * SE;
    gather_core(msg, bkt, i0, i0 + n, lane, acc);
    float inv = 1.0f / reg_sum[r];
    acc.x *= inv; acc.y *= inv; acc.z *= inv; acc.w *= inv;
    ((float4*)(out + (size_t)r * HD))[lane] = acc;
    if (out_bf) {
        short4v s;
        s[0] = f2bf(acc.x); s[1] = f2bf(acc.y); s[2] = f2bf(acc.z); s[3] = f2bf(acc.w);
        *(short4v*)(out_bf + (size_t)r * HD + (lane << 2)) = s;
    }
}

__global__ __launch_bounds__(256) void gather_v(
    const short* __restrict__ msg,       // [NE][256] bf16
    const int2* __restrict__ bkt,        // [NV][SV] {src,w}
    const int* __restrict__ cnt,
    const float* __restrict__ v_f32, const short* __restrict__ v_bf,  // v_bf may be null
    const float* __restrict__ n_w,
    const float* __restrict__ reg_sum, float* __restrict__ out)
{
    int r    = (blockIdx.x << 2) + (threadIdx.x >> 6);
    int lane = threadIdx.x & 63;
    float nw = n_w[r];
    float4 a;
    if (v_bf) {
        short4v b = *(const short4v*)(v_bf + (size_t)r * HD + (lane << 2));
        a.x = bf2f(b[0]); a.y = bf2f(b[1]); a.z = bf2f(b[2]); a.w = bf2f(b[3]);
    } else {
        a = ((const float4*)(v_f32 + (size_t)r * HD))[lane];
    }
    float4 acc; acc.x = a.x * nw; acc.y = a.y * nw; acc.z = a.z * nw; acc.w = a.w * nw;
    int n = cnt[r]; n = n < SV ? n : SV;
    int i0 = r * SV;
    gather_core(msg, bkt, i0, i0 + n, lane, acc);
    float inv = 1.0f / reg_sum[r];
    acc.x *= inv; acc.y *= inv; acc.z *= inv; acc.w *= inv;
    ((float4*)(out + (size_t)r * HD))[lane] = acc;
}

extern "C" void kernel_launch(void* const* d_in, const int* in_sizes, int n_in,
                              void* d_out, int out_size, void* d_ws, size_t ws_size,
                              hipStream_t stream) {
    const float* v   = (const float*)d_in[0];
    const float* e   = (const float*)d_in[1];
    const float* W1  = (const float*)d_in[2];
    const float* b1  = (const float*)d_in[3];
    const float* W2  = (const float*)d_in[4];
    const float* b2  = (const float*)d_in[5];
    const float* n_weight     = (const float*)d_in[6];
    const float* e_weight     = (const float*)d_in[7];
    const float* n_reg_weight = (const float*)d_in[8];
    const float* e_reg_weight = (const float*)d_in[9];
    const float* e_reg_sum    = (const float*)d_in[10];
    const float* n_reg_sum    = (const float*)d_in[11];
    const int* pairs_v = (const int*)d_in[12];
    const int* eidx    = (const int*)d_in[13];
    const int* pairs_e = (const int*)d_in[14];
    const int* vidx    = (const int*)d_in[15];

    float* out      = (float*)d_out;
    float* v_region = out;
    float* e_region = out + (size_t)NV * HD;

    // --- workspace layout ---
    // mandatory (~55.2 MB): msg, int2 buckets (inline metadata), W_bf,
    // cnt8|e_bf union (7.68 MB), counts. optional: +v_bf (25.6 MB) -> ~80.8 MB.
    char* ws = (char*)d_ws;
    size_t o = 0;
    short* msg     = (short*)(ws + o); o += (size_t)NV * HD * 2;        // 25.6 MB
    int2*  bkt_e   = (int2*)(ws + o);  o += (size_t)NE * SE * 8;        // 7.04 MB
    int2*  bkt_v   = (int2*)(ws + o);  o += (size_t)NV * SV * 8;        // 14.4 MB
    short* W_bf    = (short*)(ws + o); o += (size_t)2 * 65536 * 2;      // 256 KB
    int*   cnt8    = (int*)(ws + o);                                    // 7.68 MB ─┐ union
    short* e_bf    = (short*)(ws + o); o += (size_t)NCH * NW * 4;       //          ─┘
    int*   cnt_e   = (int*)(ws + o);   o += (size_t)NE * 4;             // 40 KB
    int*   cnt_v   = (int*)(ws + o);   o += (size_t)NV * 4;             // 200 KB
    size_t o_opt = o;
    short* v_bf    = (short*)(ws + o_opt);
    size_t need_full = o_opt + (size_t)NV * HD * 2;
    const int full = (ws_size >= need_full);   // launch-invariant -> graph-safe

    // 1) converts + per-chunk histograms (no device atomics, no memset needed)
    prep_kernel<<<PREP_HBLK + PREP_WBLK + PREP_VBLK, 1024, 0, stream>>>(
        v, W1, W2, eidx, vidx, full ? v_bf : (short*)msg /*unused*/, W_bf,
        cnt8, full);
    // 2) chunk-prefix scan -> starts (in-place) + row totals
    scan_kernel<<<(NW + 255) / 256, 256, 0, stream>>>(cnt8, cnt_e, cnt_v);
    // 3) exact-slot placement, e/v split across 256 blocks; metadata inlined
    place_kernel<<<2 * NCH, 1024, 0, stream>>>(
        eidx, vidx, pairs_v, (const int*)n_reg_weight,
        pairs_e, (const int*)e_reg_weight, cnt8, bkt_e, bkt_v);

    // msg = bf16( relu(v @ W1^T + b1) * n_weight )
    gemm_rs<<<(NV + 63) / 64, 256, 0, stream>>>(
        full ? (const void*)v_bf : (const void*)v, full, W_bf, b1, n_weight, msg, NV);
    // e_out = (e + gather(msg)) / e_reg_sum   (+ bf16 copy; overwrites cnt8 region)
    gather_e<<<NE / 4, 256, 0, stream>>>(msg, bkt_e, cnt_e,
        e, e_reg_sum, e_region, e_bf);
    // msg = bf16( relu(e_out @ W2^T + b2) * e_weight )
    gemm_rs<<<(NE + 63) / 64, 256, 0, stream>>>(
        (const void*)e_bf, 1, W_bf + 65536, b2, e_weight, msg, NE);
    // v_out = (v*n_weight + gather(msg)) / n_reg_sum
    gather_v<<<NV / 4, 256, 0, stream>>>(msg, bkt_v, cnt_v,
        v, full ? v_bf : (short*)0, n_weight, n_reg_sum, v_region);
}

// Round 7
// 282.510 us; speedup vs baseline: 1.0072x; 1.0072x over previous
//
#include <hip/hip_runtime.h>
#include <stdint.h>

#define NV 50000
#define NE 10000
#define HD 256
#define NP 400000

#define SE 88     // bkt_e row stride (avg deg 40; P[any row >88] ~ 1e-7)
#define SV 36     // bkt_v row stride (avg deg 8;  P[any row >36] ~ 3e-9)

#define NCH 128           // chunks for the no-atomic counting sort
#define CHP (NP / NCH)    // 3125 pairs per chunk
#define NW  15000         // packed words (4 rows/word, 8-bit ctrs); e:[0,2500) v:[2500,15000)
#define NWE 2500
#define NWV 12500

#define PREP_HBLK NCH     // hist blocks (LDS-only, no device atomics)
#define PREP_WBLK 16      // W1+W2 convert: 131072 elems / 8192

typedef short short8 __attribute__((ext_vector_type(8)));
typedef short short4v __attribute__((ext_vector_type(4)));
typedef float f32x4 __attribute__((ext_vector_type(4)));

__device__ __forceinline__ short f2bf(float f) {
    unsigned int u = __builtin_bit_cast(unsigned int, f);
    u += 0x7FFFu + ((u >> 16) & 1u);   // round-to-nearest-even
    return (short)(u >> 16);
}
__device__ __forceinline__ float bf2f(short s) {
    unsigned int u = ((unsigned int)(unsigned short)s) << 16;
    return __builtin_bit_cast(float, u);
}

// ---------------------------------------------------------------------------
// prep: per-chunk histogram (LDS, packed 8-bit) + (W1,W2 -> bf16).
// v-convert removed: gemm1 now emits v_bf as a side-product of its A staging.
// ---------------------------------------------------------------------------
__global__ __launch_bounds__(1024) void prep_kernel(
    const float* __restrict__ W1, const float* __restrict__ W2,
    const int* __restrict__ eidx, const int* __restrict__ vidx,
    short* __restrict__ W_bf,       // [2*256*256]
    int* __restrict__ cnt8)         // [NCH][NW] packed counts
{
    __shared__ int h[NW];   // 60 KB
    int b = blockIdx.x;
    int tid = threadIdx.x;
    if (b < PREP_HBLK) {
        for (int w = tid; w < NW; w += 1024) h[w] = 0;
        __syncthreads();
        int base = b * CHP;
        for (int k = tid; k < CHP; k += 1024) {
            int p = base + k;
            int er = eidx[p];
            atomicAdd((unsigned*)&h[er >> 2], 1u << ((er & 3) * 8));
            int rv = 10000 + vidx[p];
            atomicAdd((unsigned*)&h[rv >> 2], 1u << ((rv & 3) * 8));
        }
        __syncthreads();
        for (int w = tid; w < NW; w += 1024) cnt8[b * NW + w] = h[w];
    } else {
        size_t i = (size_t)(b - PREP_HBLK) * 8192 + (size_t)tid * 8;
        const float* src = (i < 65536) ? (W1 + i) : (W2 + (i - 65536));
        float4 a0 = *(const float4*)src;
        float4 a1 = *(const float4*)(src + 4);
        short8 s;
        s[0] = f2bf(a0.x); s[1] = f2bf(a0.y); s[2] = f2bf(a0.z); s[3] = f2bf(a0.w);
        s[4] = f2bf(a1.x); s[5] = f2bf(a1.y); s[6] = f2bf(a1.z); s[7] = f2bf(a1.w);
        *(short8*)(W_bf + i) = s;
    }
}

// ---------------------------------------------------------------------------
// scan: per-word SWAR exclusive prefix over chunks (byte lanes never carry:
// row totals <= 255). Overwrites cnt8 with per-chunk starts; emits totals.
// ---------------------------------------------------------------------------
__global__ __launch_bounds__(256) void scan_kernel(
    int* __restrict__ cnt8, int* __restrict__ cnt_e, int* __restrict__ cnt_v)
{
    int w = blockIdx.x * 256 + threadIdx.x;
    if (w >= NW) return;
    unsigned acc = 0;
#pragma unroll 8
    for (int c = 0; c < NCH; ++c) {
        unsigned x = (unsigned)cnt8[c * NW + w];
        cnt8[c * NW + w] = (int)acc;
        acc += x;
    }
    int r0 = w * 4;
    int4 t;
    t.x = acc & 0xFF; t.y = (acc >> 8) & 0xFF; t.z = (acc >> 16) & 0xFF; t.w = acc >> 24;
    if (r0 < 10000) *(int4*)&cnt_e[r0] = t;
    else            *(int4*)&cnt_v[r0 - 10000] = t;
}

// ---------------------------------------------------------------------------
// place: 256 blocks, e-side (b<NCH) and v-side (b>=NCH) split. Exact slot via
// packed LDS fetch-add, stores gather metadata INLINE: {src_row, weight_bits}.
// All p-indexed inputs read sequentially (coalesced); zero device atomics.
// ---------------------------------------------------------------------------
__global__ __launch_bounds__(1024) void place_kernel(
    const int* __restrict__ eidx, const int* __restrict__ vidx,
    const int* __restrict__ pairs_v, const int* __restrict__ n_reg_w_bits,
    const int* __restrict__ pairs_e, const int* __restrict__ e_reg_w_bits,
    const int* __restrict__ cnt8,
    int2* __restrict__ bkt_e, int2* __restrict__ bkt_v)
{
    __shared__ int h[NWV];   // 50 KB (v-side); e-side uses first 2500 words
    int b = blockIdx.x;
    int tid = threadIdx.x;
    if (b < NCH) {
        int c = b;
        for (int w = tid; w < NWE; w += 1024) h[w] = cnt8[c * NW + w];
        __syncthreads();
        int base = c * CHP;
        for (int k = tid; k < CHP; k += 1024) {
            int p = base + k;
            int er = eidx[p];
            unsigned old = atomicAdd((unsigned*)&h[er >> 2], 1u << ((er & 3) * 8));
            int s = (old >> ((er & 3) * 8)) & 0xFF;
            if (s < SE) bkt_e[er * SE + s] = make_int2(pairs_v[p], n_reg_w_bits[p]);
        }
    } else {
        int c = b - NCH;
        for (int w = tid; w < NWV; w += 1024) h[w] = cnt8[c * NW + NWE + w];
        __syncthreads();
        int base = c * CHP;
        for (int k = tid; k < CHP; k += 1024) {
            int p = base + k;
            int vr = vidx[p];
            unsigned old = atomicAdd((unsigned*)&h[vr >> 2], 1u << ((vr & 3) * 8));
            int s = (old >> ((vr & 3) * 8)) & 0xFF;
            if (s < SV) bkt_v[vr * SV + s] = make_int2(pairs_e[p], e_reg_w_bits[p]);
        }
    }
}

// ---------------------------------------------------------------------------
// GEMM: out_bf16[i][j] = relu(sum_k A[i][k]*W[j][k] + bias[j]) * rowscale[i]
// A: [M][256] f32 or bf16 (a_bf flag). When a_bf=0 and a_out!=0, the staged
// bf16 A tile is also written to a_out (free v_bf production inside gemm1).
// ---------------------------------------------------------------------------
__global__ __launch_bounds__(256) void gemm_rs(
    const void* __restrict__ Av, int a_bf,
    const short* __restrict__ Wb,
    const float* __restrict__ bias,
    const float* __restrict__ rowscale,
    short* __restrict__ out,          // bf16
    short* __restrict__ a_out,        // optional bf16 copy of A (may be null)
    int M)
{
    __shared__ short As[64 * 256];
    __shared__ short Ws[64 * 256];
    const int tid  = threadIdx.x;
    const int row0 = blockIdx.x * 64;

    // stage A tile once
#pragma unroll
    for (int it = 0; it < 8; ++it) {
        int cl = it * 256 + tid;
        int r  = cl >> 5;
        int c  = cl & 31;
        int gr0 = row0 + r;
        int gr  = gr0 < M ? gr0 : M - 1;
        short8 ap;
        if (a_bf) {
            ap = *(const short8*)((const short*)Av + (size_t)gr * HD + (c << 3));
        } else {
            const float* asrc = (const float*)Av + (size_t)gr * HD + (c << 3);
            float4 a0 = *(const float4*)asrc;
            float4 a1 = *(const float4*)(asrc + 4);
            ap[0] = f2bf(a0.x); ap[1] = f2bf(a0.y); ap[2] = f2bf(a0.z); ap[3] = f2bf(a0.w);
            ap[4] = f2bf(a1.x); ap[5] = f2bf(a1.y); ap[6] = f2bf(a1.z); ap[7] = f2bf(a1.w);
            if (a_out && gr0 < M)
                *(short8*)(a_out + (size_t)gr0 * HD + (c << 3)) = ap;
        }
        *(short8*)&As[(r << 8) + ((c ^ (r & 7)) << 3)] = ap;
    }

    const int lane = tid & 63;
    const int wv   = tid >> 6;
    const int m16  = lane & 15;
    const int quad = lane >> 4;
    const int arow = (wv << 4) + m16;

    for (int ct = 0; ct < 4; ++ct) {
        __syncthreads();
#pragma unroll
        for (int it = 0; it < 8; ++it) {
            int cl = it * 256 + tid;
            int r  = cl >> 5;
            int c  = cl & 31;
            short8 wp = *(const short8*)(Wb + (size_t)((ct << 6) + r) * HD + (c << 3));
            *(short8*)&Ws[(r << 8) + ((c ^ (r & 7)) << 3)] = wp;
        }
        __syncthreads();

        f32x4 acc[4];
#pragma unroll
        for (int nt = 0; nt < 4; ++nt) acc[nt] = (f32x4){0.f, 0.f, 0.f, 0.f};

#pragma unroll
        for (int ks = 0; ks < 8; ++ks) {
            int c = (ks << 2) + quad;
            short8 afr = *(const short8*)&As[(arow << 8) + ((c ^ (arow & 7)) << 3)];
#pragma unroll
            for (int nt = 0; nt < 4; ++nt) {
                int brow = (nt << 4) + m16;
                short8 bfr = *(const short8*)&Ws[(brow << 8) + ((c ^ (m16 & 7)) << 3)];
                acc[nt] = __builtin_amdgcn_mfma_f32_16x16x32_bf16(afr, bfr, acc[nt], 0, 0, 0);
            }
        }

#pragma unroll
        for (int r = 0; r < 4; ++r) {
            int row = row0 + (wv << 4) + (quad << 2) + r;
            if (row < M) {
                float rs = rowscale[row];
#pragma unroll
                for (int nt = 0; nt < 4; ++nt) {
                    int col = (ct << 6) + (nt << 4) + m16;
                    float val = acc[nt][r] + bias[col];
                    val = fmaxf(val, 0.0f) * rs;
                    out[(size_t)row * HD + col] = f2bf(val);
                }
            }
        }
    }
}

// ---------------------------------------------------------------------------
// gather window: metadata for up to 64 entries already resident in registers
// (src/wb per lane, loaded speculatively before cnt resolved -> one fewer
// serial memory round-trip). 8-deep unroll = 8 scattered loads in flight;
// dual accumulators halve the serial FMA chain.
// ---------------------------------------------------------------------------
__device__ __forceinline__ void gather_win(
    const short* __restrict__ msg, int src, int wb, int cnt, int lane,
    float4& A, float4& B)
{
    int j = 0;
    for (; j + 8 <= cnt; j += 8) {
        int s0 = __shfl(src, j),     s1 = __shfl(src, j + 1);
        int s2 = __shfl(src, j + 2), s3 = __shfl(src, j + 3);
        int s4 = __shfl(src, j + 4), s5 = __shfl(src, j + 5);
        int s6 = __shfl(src, j + 6), s7 = __shfl(src, j + 7);
        float w0 = __builtin_bit_cast(float, __shfl(wb, j));
        float w1 = __builtin_bit_cast(float, __shfl(wb, j + 1));
        float w2 = __builtin_bit_cast(float, __shfl(wb, j + 2));
        float w3 = __builtin_bit_cast(float, __shfl(wb, j + 3));
        float w4 = __builtin_bit_cast(float, __shfl(wb, j + 4));
        float w5 = __builtin_bit_cast(float, __shfl(wb, j + 5));
        float w6 = __builtin_bit_cast(float, __shfl(wb, j + 6));
        float w7 = __builtin_bit_cast(float, __shfl(wb, j + 7));
        short4v m0 = *(const short4v*)(msg + ((size_t)s0 << 8) + (lane << 2));
        short4v m1 = *(const short4v*)(msg + ((size_t)s1 << 8) + (lane << 2));
        short4v m2 = *(const short4v*)(msg + ((size_t)s2 << 8) + (lane << 2));
        short4v m3 = *(const short4v*)(msg + ((size_t)s3 << 8) + (lane << 2));
        short4v m4 = *(const short4v*)(msg + ((size_t)s4 << 8) + (lane << 2));
        short4v m5 = *(const short4v*)(msg + ((size_t)s5 << 8) + (lane << 2));
        short4v m6 = *(const short4v*)(msg + ((size_t)s6 << 8) + (lane << 2));
        short4v m7 = *(const short4v*)(msg + ((size_t)s7 << 8) + (lane << 2));
        A.x += bf2f(m0[0]) * w0; A.y += bf2f(m0[1]) * w0;
        A.z += bf2f(m0[2]) * w0; A.w += bf2f(m0[3]) * w0;
        B.x += bf2f(m1[0]) * w1; B.y += bf2f(m1[1]) * w1;
        B.z += bf2f(m1[2]) * w1; B.w += bf2f(m1[3]) * w1;
        A.x += bf2f(m2[0]) * w2; A.y += bf2f(m2[1]) * w2;
        A.z += bf2f(m2[2]) * w2; A.w += bf2f(m2[3]) * w2;
        B.x += bf2f(m3[0]) * w3; B.y += bf2f(m3[1]) * w3;
        B.z += bf2f(m3[2]) * w3; B.w += bf2f(m3[3]) * w3;
        A.x += bf2f(m4[0]) * w4; A.y += bf2f(m4[1]) * w4;
        A.z += bf2f(m4[2]) * w4; A.w += bf2f(m4[3]) * w4;
        B.x += bf2f(m5[0]) * w5; B.y += bf2f(m5[1]) * w5;
        B.z += bf2f(m5[2]) * w5; B.w += bf2f(m5[3]) * w5;
        A.x += bf2f(m6[0]) * w6; A.y += bf2f(m6[1]) * w6;
        A.z += bf2f(m6[2]) * w6; A.w += bf2f(m6[3]) * w6;
        B.x += bf2f(m7[0]) * w7; B.y += bf2f(m7[1]) * w7;
        B.z += bf2f(m7[2]) * w7; B.w += bf2f(m7[3]) * w7;
    }
    for (; j + 2 <= cnt; j += 2) {
        int s0 = __shfl(src, j), s1 = __shfl(src, j + 1);
        float w0 = __builtin_bit_cast(float, __shfl(wb, j));
        float w1 = __builtin_bit_cast(float, __shfl(wb, j + 1));
        short4v m0 = *(const short4v*)(msg + ((size_t)s0 << 8) + (lane << 2));
        short4v m1 = *(const short4v*)(msg + ((size_t)s1 << 8) + (lane << 2));
        A.x += bf2f(m0[0]) * w0; A.y += bf2f(m0[1]) * w0;
        A.z += bf2f(m0[2]) * w0; A.w += bf2f(m0[3]) * w0;
        B.x += bf2f(m1[0]) * w1; B.y += bf2f(m1[1]) * w1;
        B.z += bf2f(m1[2]) * w1; B.w += bf2f(m1[3]) * w1;
    }
    if (j < cnt) {
        int s0 = __shfl(src, j);
        float w0 = __builtin_bit_cast(float, __shfl(wb, j));
        short4v m0 = *(const short4v*)(msg + ((size_t)s0 << 8) + (lane << 2));
        A.x += bf2f(m0[0]) * w0; A.y += bf2f(m0[1]) * w0;
        A.z += bf2f(m0[2]) * w0; A.w += bf2f(m0[3]) * w0;
    }
}

__global__ __launch_bounds__(256) void gather_e(
    const short* __restrict__ msg,       // [NV][256] bf16
    const int2* __restrict__ bkt,        // [NE][SE] {src,w} (+64 pad)
    const int* __restrict__ cnt,
    const float* __restrict__ e_in, const float* __restrict__ reg_sum,
    float* __restrict__ out, short* __restrict__ out_bf)
{
    int r    = (blockIdx.x << 2) + (threadIdx.x >> 6);
    int lane = threadIdx.x & 63;
    int i0 = r * SE;
    int2 q = bkt[i0 + lane];             // speculative window 0 (padded)
    int n = cnt[r]; n = n < SE ? n : SE;
    float4 A = ((const float4*)(e_in + (size_t)r * HD))[lane];
    float4 B = {0.f, 0.f, 0.f, 0.f};
    float inv = 1.0f / reg_sum[r];
    int n0 = n < 64 ? n : 64;
    gather_win(msg, q.x, q.y, n0, lane, A, B);
    if (n > 64) {
        int2 q2 = make_int2(0, 0);
        if (lane < SE - 64) q2 = bkt[i0 + 64 + lane];
        gather_win(msg, q2.x, q2.y, n - 64, lane, A, B);
    }
    float4 acc;
    acc.x = (A.x + B.x) * inv; acc.y = (A.y + B.y) * inv;
    acc.z = (A.z + B.z) * inv; acc.w = (A.w + B.w) * inv;
    ((float4*)(out + (size_t)r * HD))[lane] = acc;
    if (out_bf) {
        short4v s;
        s[0] = f2bf(acc.x); s[1] = f2bf(acc.y); s[2] = f2bf(acc.z); s[3] = f2bf(acc.w);
        *(short4v*)(out_bf + (size_t)r * HD + (lane << 2)) = s;
    }
}

__global__ __launch_bounds__(256) void gather_v(
    const short* __restrict__ msg,       // [NE][256] bf16
    const int2* __restrict__ bkt,        // [NV][SV] {src,w} (+64 pad)
    const int* __restrict__ cnt,
    const float* __restrict__ v_f32, const short* __restrict__ v_bf,
    const float* __restrict__ n_w,
    const float* __restrict__ reg_sum, float* __restrict__ out)
{
    int r    = (blockIdx.x << 2) + (threadIdx.x >> 6);
    int lane = threadIdx.x & 63;
    int i0 = r * SV;
    int2 q = bkt[i0 + lane];             // speculative window 0 (padded)
    int n = cnt[r]; n = n < SV ? n : SV;
    float nw = n_w[r];
    float inv = 1.0f / reg_sum[r];
    float4 a;
    if (v_bf) {
        short4v b = *(const short4v*)(v_bf + (size_t)r * HD + (lane << 2));
        a.x = bf2f(b[0]); a.y = bf2f(b[1]); a.z = bf2f(b[2]); a.w = bf2f(b[3]);
    } else {
        a = ((const float4*)(v_f32 + (size_t)r * HD))[lane];
    }
    float4 A; A.x = a.x * nw; A.y = a.y * nw; A.z = a.z * nw; A.w = a.w * nw;
    float4 B = {0.f, 0.f, 0.f, 0.f};
    gather_win(msg, q.x, q.y, n, lane, A, B);
    float4 acc;
    acc.x = (A.x + B.x) * inv; acc.y = (A.y + B.y) * inv;
    acc.z = (A.z + B.z) * inv; acc.w = (A.w + B.w) * inv;
    ((float4*)(out + (size_t)r * HD))[lane] = acc;
}

extern "C" void kernel_launch(void* const* d_in, const int* in_sizes, int n_in,
                              void* d_out, int out_size, void* d_ws, size_t ws_size,
                              hipStream_t stream) {
    const float* v   = (const float*)d_in[0];
    const float* e   = (const float*)d_in[1];
    const float* W1  = (const float*)d_in[2];
    const float* b1  = (const float*)d_in[3];
    const float* W2  = (const float*)d_in[4];
    const float* b2  = (const float*)d_in[5];
    const float* n_weight     = (const float*)d_in[6];
    const float* e_weight     = (const float*)d_in[7];
    const float* n_reg_weight = (const float*)d_in[8];
    const float* e_reg_weight = (const float*)d_in[9];
    const float* e_reg_sum    = (const float*)d_in[10];
    const float* n_reg_sum    = (const float*)d_in[11];
    const int* pairs_v = (const int*)d_in[12];
    const int* eidx    = (const int*)d_in[13];
    const int* pairs_e = (const int*)d_in[14];
    const int* vidx    = (const int*)d_in[15];

    float* out      = (float*)d_out;
    float* v_region = out;
    float* e_region = out + (size_t)NV * HD;

    // --- workspace layout ---
    // mandatory (~55.2 MB): msg, padded int2 buckets, W_bf, cnt8|e_bf union,
    // counts. optional: +v_bf (25.6 MB) -> ~80.8 MB.
    char* ws = (char*)d_ws;
    size_t o = 0;
    short* msg     = (short*)(ws + o); o += (size_t)NV * HD * 2;            // 25.6 MB
    int2*  bkt_e   = (int2*)(ws + o);  o += ((size_t)NE * SE + 64) * 8;     // 7.04 MB
    int2*  bkt_v   = (int2*)(ws + o);  o += ((size_t)NV * SV + 64) * 8;     // 14.4 MB
    short* W_bf    = (short*)(ws + o); o += (size_t)2 * 65536 * 2;          // 256 KB
    int*   cnt8    = (int*)(ws + o);                                        // 7.68 MB ─┐ union
    short* e_bf    = (short*)(ws + o); o += (size_t)NCH * NW * 4;           //          ─┘
    int*   cnt_e   = (int*)(ws + o);   o += (size_t)NE * 4;                 // 40 KB
    int*   cnt_v   = (int*)(ws + o);   o += (size_t)NV * 4;                 // 200 KB
    size_t o_opt = o;
    short* v_bf    = (short*)(ws + o_opt);
    size_t need_full = o_opt + (size_t)NV * HD * 2;
    const int full = (ws_size >= need_full);   // launch-invariant -> graph-safe

    // 1) W converts + per-chunk histograms (no device atomics, no memset)
    prep_kernel<<<PREP_HBLK + PREP_WBLK, 1024, 0, stream>>>(
        W1, W2, eidx, vidx, W_bf, cnt8);
    // 2) chunk-prefix scan -> starts (in-place) + row totals
    scan_kernel<<<(NW + 255) / 256, 256, 0, stream>>>(cnt8, cnt_e, cnt_v);
    // 3) exact-slot placement, e/v split across 256 blocks; metadata inlined
    place_kernel<<<2 * NCH, 1024, 0, stream>>>(
        eidx, vidx, pairs_v, (const int*)n_reg_weight,
        pairs_e, (const int*)e_reg_weight, cnt8, bkt_e, bkt_v);

    // msg = bf16( relu(v @ W1^T + b1) * n_weight ); also emits v_bf when full
    gemm_rs<<<(NV + 63) / 64, 256, 0, stream>>>(
        (const void*)v, 0, W_bf, b1, n_weight, msg, full ? v_bf : (short*)0, NV);
    // e_out = (e + gather(msg)) / e_reg_sum   (+ bf16 copy; overwrites cnt8)
    gather_e<<<NE / 4, 256, 0, stream>>>(msg, bkt_e, cnt_e,
        e, e_reg_sum, e_region, e_bf);
    // msg = bf16( relu(e_out @ W2^T + b2) * e_weight )
    gemm_rs<<<(NE + 63) / 64, 256, 0, stream>>>(
        (const void*)e_bf, 1, W_bf + 65536, b2, e_weight, msg, (short*)0, NE);
    // v_out = (v*n_weight + gather(msg)) / n_reg_sum
    gather_v<<<NV / 4, 256, 0, stream>>>(msg, bkt_v, cnt_v,
        v, full ? v_bf : (short*)0, n_weight, n_reg_sum, v_region);
}